// Round 10
// baseline (4558.972 us; speedup 1.0000x reference)
//
#include <hip/hip_runtime.h>
#include <hip/hip_bf16.h>

// ScalarBorn: 4th-order FD scalar wave + Born scattering with CPML, MI355X.
// R10: R9 skeleton (256 thr x 2 pts, 2 barriers) but TWO rows per block:
// 888 blocks; shared 6-row register column serves both rows' y-stencils
// (interior y-loads 20->12 float2/thread). Frame strips (22/222) use the
// R9 per-row path. Issue-bound regime confirmed by R7 (load cut: +2.8%)
// vs R9 (instr cut: +23%); R8 showed register-heavy blocks regress.

constexpr int NYX  = 400;
constexpr int NS   = 4;
constexpr int NREC = 100;
constexpr int NT   = 300;
constexpr int PAD  = 22;
constexpr int NP   = 444;
constexpr int NP2  = NP * NP;          // 197136
constexpr int SNP2 = NS * NP2;         // 788544
constexpr float DT    = 0.0005f;
constexpr float INVH  = 0.2f;          // 1/DX
constexpr float INVH2 = 0.04f;         // 1/DX^2
constexpr float C1A = 1.0f / 12.0f;
constexpr float C1B = 2.0f / 3.0f;
constexpr float C2A = -1.0f / 12.0f;
constexpr float C2B = 4.0f / 3.0f;
constexpr float C2C = -2.5f;

__device__ __align__(16) float g_wb[2][SNP2];      // bg field ping-pong
__device__ __align__(16) float g_ws[2][SNP2];      // scattered field ping-pong
__device__ __align__(16) float g_psi[2][4][SNP2];  // [buf][py_b,px_b,py_s,px_s]
__device__ __align__(16) float g_zeta[4][SNP2];    // [zy_b,zx_b,zy_s,zx_s]
__device__ float g_v2dt2[NP2];
__device__ float g_bscale[NP2];
__device__ float g_pa[NP];
__device__ float g_pb[NP];
__device__ float g_fbg[NT * NS];
__device__ float g_fsc[NT * NS];
__device__ int   g_spos[2 * NS];
__device__ int   g_mode;               // 1 = bf16 io, 0 = f32 io

__device__ __forceinline__ int clampi(int v, int lo, int hi) {
    return v < lo ? lo : (v > hi ? hi : v);
}
__device__ __forceinline__ float in_ld(const void* p, int i) {
    if (g_mode) return __bfloat162float(((const __hip_bfloat16*)p)[i]);
    return ((const float*)p)[i];
}
__device__ __forceinline__ void out_st(void* p, int i, float v) {
    if (g_mode) ((__hip_bfloat16*)p)[i] = __float2bfloat16(v);
    else        ((float*)p)[i] = v;
}
// float2 row load at columns (2i, 2i+1) of row y; zero outside [0,NP)
__device__ __forceinline__ float2 ld2(const float* w, int y, int i) {
    if ((unsigned)y >= (unsigned)NP) return make_float2(0.f, 0.f);
    return *(const float2*)(w + y * NP + 2 * i);
}

__global__ void detect_mode(const void* vptr) {
    if (threadIdx.x == 0 && blockIdx.x == 0) {
        const __hip_bfloat16* p = (const __hip_bfloat16*)vptr;
        int ok = 1;
        for (int i = 0; i < 32; i += 2) {
            float f = __bfloat162float(p[i]);
            if (!(f >= 1000.f && f <= 3000.f)) ok = 0;
        }
        g_mode = ok;
    }
}

__global__ void zero_state() {
    int i = blockIdx.x * blockDim.x + threadIdx.x;
    if (i >= NP2) return;                 // SNP2/4 float4s per array == NP2
    float4 z = make_float4(0.f, 0.f, 0.f, 0.f);
    ((float4*)g_wb[0])[i] = z;  ((float4*)g_wb[1])[i] = z;
    ((float4*)g_ws[0])[i] = z;  ((float4*)g_ws[1])[i] = z;
    #pragma unroll
    for (int b = 0; b < 2; ++b)
        #pragma unroll
        for (int k = 0; k < 4; ++k) ((float4*)g_psi[b][k])[i] = z;
    #pragma unroll
    for (int k = 0; k < 4; ++k) ((float4*)g_zeta[k])[i] = z;
}

__global__ void prep_pad(const void* __restrict__ v, const void* __restrict__ sc) {
    int i = blockIdx.x * blockDim.x + threadIdx.x;
    if (i >= NP2) return;
    int y = i / NP, x = i % NP;
    int vy = clampi(y - PAD, 0, NYX - 1);
    int vx = clampi(x - PAD, 0, NYX - 1);
    float vv = in_ld(v, vy * NYX + vx);
    float vd = vv * DT;
    g_v2dt2[i] = vd * vd;
    float s = 0.f;
    if (y >= PAD && y < PAD + NYX && x >= PAD && x < PAD + NYX)
        s = in_ld(sc, (y - PAD) * NYX + (x - PAD));
    g_bscale[i] = 2.f * vv * s * DT * DT;
    if (i < NP) {
        float fi = (float)i;
        float f1 = fminf(fmaxf((22.f - fi) * 0.05f, 0.f), 1.f);
        float f2 = fminf(fmaxf((fi - 421.f) * 0.05f, 0.f), 1.f);
        float frac = fmaxf(f1, f2);
        float sigma = 259.0408229f * frac * frac;
        const float alpha = 78.53981634f;
        float a = expf(-(sigma + alpha) * DT);
        g_pa[i] = a;
        g_pb[i] = (sigma > 0.f) ? sigma / (sigma + alpha) * (a - 1.f) : 0.f;
    }
}

__global__ void prep_src(const void* __restrict__ amp, const int* __restrict__ sloc,
                         const void* __restrict__ v, const void* __restrict__ sc) {
    int i = blockIdx.x * blockDim.x + threadIdx.x;
    if (i >= NT * NS) return;
    int s = i % NS, t = i / NS;
    int ly = clampi(sloc[s * 2 + 0], 0, NYX - 1);
    int lx = clampi(sloc[s * 2 + 1], 0, NYX - 1);
    float a  = in_ld(amp, s * NT + t);
    float vv = in_ld(v,  ly * NYX + lx);
    float ss = in_ld(sc, ly * NYX + lx);
    g_fbg[i] = -a * vv * vv * DT * DT;
    g_fsc[i] = -2.f * a * vv * ss * DT * DT;
    if (i < NS) {
        g_spos[2 * i]     = ly + PAD;
        g_spos[2 * i + 1] = lx + PAD;
    }
}

// one fused timestep. Block = rows {2*strip, 2*strip+1} of shot s.
__global__ void __launch_bounds__(256)
step_fused(int t, const int* __restrict__ rloc, const int* __restrict__ rbloc,
           void* __restrict__ out) {
    const int i  = threadIdx.x;
    const int y0 = 2 * blockIdx.y;
    const int s  = blockIdx.z;
    const int cur = t & 1, nxt = cur ^ 1;
    __shared__ float swb[2][452], sws[2][452], spxb[2][452], spxs[2][452];

    if (t > 0 && blockIdx.y == 0 && i < 2 * NREC) {   // record step t-1
        int r = i % NREC;
        bool isbg = i < NREC;
        const int* rl = isbg ? rbloc : rloc;
        int ry = clampi(rl[(s * NREC + r) * 2 + 0], 0, NYX - 1) + PAD;
        int rx = clampi(rl[(s * NREC + r) * 2 + 1], 0, NYX - 1) + PAD;
        const float* w = isbg ? g_wb[cur] : g_ws[cur];
        float val = w[s * NP2 + ry * NP + rx];
        int base = isbg ? (2 * SNP2) : (2 * SNP2 + NS * NREC * NT);
        out_st(out, base + (s * NREC + r) * NT + (t - 1), val);
    }

    const bool active = i < 222;
    const int x0 = 2 * i, x1 = x0 + 1;
    const float* wb  = g_wb[cur] + s * NP2;
    const float* wsc = g_ws[cur] + s * NP2;
    const bool frame = (y0 <= 23 || y0 + 1 >= 420);   // block-uniform

    // ---- phase 1: load shared 6-row column (y0-2..y0+3), stage w rows ----
    float2 cb[6], cs[6];
    if (active) {
        #pragma unroll
        for (int k = 0; k < 6; ++k) {
            cb[k] = ld2(wb,  y0 - 2 + k, i);
            cs[k] = ld2(wsc, y0 - 2 + k, i);
        }
        #pragma unroll
        for (int r = 0; r < 2; ++r) {
            swb[r][x0 + 2] = cb[2 + r].x;  swb[r][x0 + 3] = cb[2 + r].y;
            sws[r][x0 + 2] = cs[2 + r].x;  sws[r][x0 + 3] = cs[2 + r].y;
        }
    } else if (i == 222) {
        #pragma unroll
        for (int r = 0; r < 2; ++r) {
            swb[r][0] = swb[r][1] = 0.f;   sws[r][0] = sws[r][1] = 0.f;
            spxb[r][0] = spxb[r][1] = 0.f; spxs[r][0] = spxs[r][1] = 0.f;
        }
    } else if (i == 223) {
        #pragma unroll
        for (int r = 0; r < 2; ++r)
            #pragma unroll
            for (int k = 446; k < 452; ++k) {
                swb[r][k] = 0.f; sws[r][k] = 0.f; spxb[r][k] = 0.f; spxs[r][k] = 0.f;
            }
    }
    __syncthreads();

    // ---- phase 2: x stencils + own psi_x updates, stage psi_x_new ----
    const bool pxreg = (i <= 11 || i >= 210);
    float pbx0 = 0.f, pbx1 = 0.f, pax0 = 0.f, pax1 = 0.f;
    float d2x_b0[2], d2x_b1[2], d2x_s0[2], d2x_s1[2];
    float pxnb0[2], pxnb1[2], pxns0[2], pxns1[2];
    if (active) {
        pbx0 = g_pb[x0]; pbx1 = g_pb[x1];
        pax0 = g_pa[x0]; pax1 = g_pa[x1];
        const int b0 = x0 + 2;
        #pragma unroll
        for (int r = 0; r < 2; ++r) {
            const int idx = s * NP2 + (y0 + r) * NP + x0;
            float bA = swb[r][b0 - 2], bB = swb[r][b0 - 1], bC = cb[2 + r].x,
                  bD = cb[2 + r].y, bE = swb[r][b0 + 2], bF = swb[r][b0 + 3];
            float sA = sws[r][b0 - 2], sB = sws[r][b0 - 1], sC = cs[2 + r].x,
                  sD = cs[2 + r].y, sE = sws[r][b0 + 2], sF = sws[r][b0 + 3];
            d2x_b0[r] = (C2A * (bA + bE) + C2B * (bB + bD) + C2C * bC) * INVH2;
            d2x_b1[r] = (C2A * (bB + bF) + C2B * (bC + bE) + C2C * bD) * INVH2;
            d2x_s0[r] = (C2A * (sA + sE) + C2B * (sB + sD) + C2C * sC) * INVH2;
            d2x_s1[r] = (C2A * (sB + sF) + C2B * (sC + sE) + C2C * sD) * INVH2;
            float nb0 = 0.f, nb1 = 0.f, ns0 = 0.f, ns1 = 0.f;
            if (pxreg) {
                float2 pxo_b = *(const float2*)(g_psi[cur][1] + idx);
                float2 pxo_s = *(const float2*)(g_psi[cur][3] + idx);
                if (pbx0 != 0.f) {
                    float dw_b = (C1A * bA - C1B * bB + C1B * bD - C1A * bE) * INVH;
                    float dw_s = (C1A * sA - C1B * sB + C1B * sD - C1A * sE) * INVH;
                    nb0 = pax0 * pxo_b.x + pbx0 * dw_b;
                    ns0 = pax0 * pxo_s.x + pbx0 * dw_s;
                    g_psi[nxt][1][idx] = nb0;
                    g_psi[nxt][3][idx] = ns0;
                }
                if (pbx1 != 0.f) {
                    float dw_b = (C1A * bB - C1B * bC + C1B * bE - C1A * bF) * INVH;
                    float dw_s = (C1A * sB - C1B * sC + C1B * sE - C1A * sF) * INVH;
                    nb1 = pax1 * pxo_b.y + pbx1 * dw_b;
                    ns1 = pax1 * pxo_s.y + pbx1 * dw_s;
                    g_psi[nxt][1][idx + 1] = nb1;
                    g_psi[nxt][3][idx + 1] = ns1;
                }
            }
            pxnb0[r] = nb0; pxnb1[r] = nb1; pxns0[r] = ns0; pxns1[r] = ns1;
            spxb[r][b0] = nb0;  spxb[r][b0 + 1] = nb1;
            spxs[r][b0] = ns0;  spxs[r][b0 + 1] = ns1;
        }
    }
    __syncthreads();
    if (!active) return;

    // ---- phase 3: per-row dpsi_x, y-part, zeta, leapfrog ----
    #pragma unroll
    for (int r = 0; r < 2; ++r) {
        const int y   = y0 + r;
        const int yx  = y * NP + x0;
        const int idx = s * NP2 + yx;
        const float2 wvb = cb[2 + r], wvs = cs[2 + r];
        const float pby = g_pb[y];

        float dpx_b0 = 0.f, dpx_b1 = 0.f, dpx_s0 = 0.f, dpx_s1 = 0.f;
        if (pxreg) {
            const int b0 = x0 + 2;
            float pA = spxb[r][b0 - 2], pB = spxb[r][b0 - 1],
                  pE = spxb[r][b0 + 2], pF = spxb[r][b0 + 3];
            float qA = spxs[r][b0 - 2], qB = spxs[r][b0 - 1],
                  qE = spxs[r][b0 + 2], qF = spxs[r][b0 + 3];
            dpx_b0 = (C1A * pA - C1B * pB + C1B * pxnb1[r] - C1A * pE) * INVH;
            dpx_b1 = (C1A * pB - C1B * pxnb0[r] + C1B * pE - C1A * pF) * INVH;
            dpx_s0 = (C1A * qA - C1B * qB + C1B * pxns1[r] - C1A * qE) * INVH;
            dpx_s1 = (C1A * qB - C1B * pxns0[r] + C1B * qE - C1A * qF) * INVH;
        }

        float d2y_b0, d2y_b1, d2y_s0, d2y_s1;
        float dpy_b0 = 0.f, dpy_b1 = 0.f, dpy_s0 = 0.f, dpy_s1 = 0.f;
        if (frame && (y <= 23 || y >= 420)) {
            float2 wyb[9], wys[9];           // rows y-4..y+4
            #pragma unroll
            for (int k = 0; k < 9; ++k) {
                if (k == 4) { wyb[4] = wvb; wys[4] = wvs; }
                else        { wyb[k] = ld2(wb, y - 4 + k, i); wys[k] = ld2(wsc, y - 4 + k, i); }
            }
            d2y_b0 = (C2A * (wyb[2].x + wyb[6].x) + C2B * (wyb[3].x + wyb[5].x) + C2C * wyb[4].x) * INVH2;
            d2y_b1 = (C2A * (wyb[2].y + wyb[6].y) + C2B * (wyb[3].y + wyb[5].y) + C2C * wyb[4].y) * INVH2;
            d2y_s0 = (C2A * (wys[2].x + wys[6].x) + C2B * (wys[3].x + wys[5].x) + C2C * wys[4].x) * INVH2;
            d2y_s1 = (C2A * (wys[2].y + wys[6].y) + C2B * (wys[3].y + wys[5].y) + C2C * wys[4].y) * INVH2;
            float2 pnb[5], pns[5];           // psi_y_new at rows y-2..y+2
            #pragma unroll
            for (int k = 0; k < 5; ++k) {
                int yy = y - 2 + k;
                float pbv = ((unsigned)yy < (unsigned)NP) ? g_pb[yy] : 0.f;
                float2 b_ = make_float2(0.f, 0.f), s_ = make_float2(0.f, 0.f);
                if (pbv != 0.f) {
                    float pav = g_pa[yy];
                    float2 po0 = *(const float2*)(g_psi[cur][0] + s * NP2 + yy * NP + x0);
                    float2 po2 = *(const float2*)(g_psi[cur][2] + s * NP2 + yy * NP + x0);
                    float db0 = (C1A * wyb[k].x - C1B * wyb[k+1].x + C1B * wyb[k+3].x - C1A * wyb[k+4].x) * INVH;
                    float db1 = (C1A * wyb[k].y - C1B * wyb[k+1].y + C1B * wyb[k+3].y - C1A * wyb[k+4].y) * INVH;
                    float ds0 = (C1A * wys[k].x - C1B * wys[k+1].x + C1B * wys[k+3].x - C1A * wys[k+4].x) * INVH;
                    float ds1 = (C1A * wys[k].y - C1B * wys[k+1].y + C1B * wys[k+3].y - C1A * wys[k+4].y) * INVH;
                    b_.x = pav * po0.x + pbv * db0;  b_.y = pav * po0.y + pbv * db1;
                    s_.x = pav * po2.x + pbv * ds0;  s_.y = pav * po2.y + pbv * ds1;
                }
                pnb[k] = b_;  pns[k] = s_;
            }
            dpy_b0 = (C1A * pnb[0].x - C1B * pnb[1].x + C1B * pnb[3].x - C1A * pnb[4].x) * INVH;
            dpy_b1 = (C1A * pnb[0].y - C1B * pnb[1].y + C1B * pnb[3].y - C1A * pnb[4].y) * INVH;
            dpy_s0 = (C1A * pns[0].x - C1B * pns[1].x + C1B * pns[3].x - C1A * pns[4].x) * INVH;
            dpy_s1 = (C1A * pns[0].y - C1B * pns[1].y + C1B * pns[3].y - C1A * pns[4].y) * INVH;
            if (pby != 0.f) {
                *(float2*)(g_psi[nxt][0] + idx) = pnb[2];
                *(float2*)(g_psi[nxt][2] + idx) = pns[2];
            }
        } else {                             // interior: shared register column
            const float2 bm2 = cb[r], bm1 = cb[r + 1], bp1 = cb[r + 3], bp2 = cb[r + 4];
            const float2 sm2 = cs[r], sm1 = cs[r + 1], sp1 = cs[r + 3], sp2 = cs[r + 4];
            d2y_b0 = (C2A * (bm2.x + bp2.x) + C2B * (bm1.x + bp1.x) + C2C * wvb.x) * INVH2;
            d2y_b1 = (C2A * (bm2.y + bp2.y) + C2B * (bm1.y + bp1.y) + C2C * wvb.y) * INVH2;
            d2y_s0 = (C2A * (sm2.x + sp2.x) + C2B * (sm1.x + sp1.x) + C2C * wvs.x) * INVH2;
            d2y_s1 = (C2A * (sm2.y + sp2.y) + C2B * (sm1.y + sp1.y) + C2C * wvs.y) * INVH2;
        }

        float zy_b0 = 0.f, zy_b1 = 0.f, zy_s0 = 0.f, zy_s1 = 0.f;
        float zx_b0 = 0.f, zx_b1 = 0.f, zx_s0 = 0.f, zx_s1 = 0.f;
        if (pby != 0.f) {
            float pay = g_pa[y];
            float2 zo0 = *(const float2*)(g_zeta[0] + idx);
            float2 zo2 = *(const float2*)(g_zeta[2] + idx);
            zy_b0 = pay * zo0.x + pby * (d2y_b0 + dpy_b0);
            zy_b1 = pay * zo0.y + pby * (d2y_b1 + dpy_b1);
            zy_s0 = pay * zo2.x + pby * (d2y_s0 + dpy_s0);
            zy_s1 = pay * zo2.y + pby * (d2y_s1 + dpy_s1);
            *(float2*)(g_zeta[0] + idx) = make_float2(zy_b0, zy_b1);
            *(float2*)(g_zeta[2] + idx) = make_float2(zy_s0, zy_s1);
        }
        if (pxreg) {
            float2 zo1 = *(const float2*)(g_zeta[1] + idx);
            float2 zo3 = *(const float2*)(g_zeta[3] + idx);
            if (pbx0 != 0.f) {
                zx_b0 = pax0 * zo1.x + pbx0 * (d2x_b0[r] + dpx_b0);
                zx_s0 = pax0 * zo3.x + pbx0 * (d2x_s0[r] + dpx_s0);
                g_zeta[1][idx] = zx_b0;  g_zeta[3][idx] = zx_s0;
            }
            if (pbx1 != 0.f) {
                zx_b1 = pax1 * zo1.y + pbx1 * (d2x_b1[r] + dpx_b1);
                zx_s1 = pax1 * zo3.y + pbx1 * (d2x_s1[r] + dpx_s1);
                g_zeta[1][idx + 1] = zx_b1;  g_zeta[3][idx + 1] = zx_s1;
            }
        }

        float2 v2   = *(const float2*)(g_v2dt2 + yx);
        float2 bsc  = *(const float2*)(g_bscale + yx);
        float2 prvb = *(const float2*)(g_wb[nxt] + idx);
        float2 prvs = *(const float2*)(g_ws[nxt] + idx);
        float lap_b0 = d2y_b0 + d2x_b0[r] + dpy_b0 + dpx_b0 + zy_b0 + zx_b0;
        float lap_b1 = d2y_b1 + d2x_b1[r] + dpy_b1 + dpx_b1 + zy_b1 + zx_b1;
        float lap_s0 = d2y_s0 + d2x_s0[r] + dpy_s0 + dpx_s0 + zy_s0 + zx_s0;
        float lap_s1 = d2y_s1 + d2x_s1[r] + dpy_s1 + dpx_s1 + zy_s1 + zx_s1;
        float wn_b0 = v2.x * lap_b0 + 2.f * wvb.x - prvb.x;
        float wn_b1 = v2.y * lap_b1 + 2.f * wvb.y - prvb.y;
        float wn_s0 = v2.x * lap_s0 + 2.f * wvs.x - prvs.x + bsc.x * lap_b0;
        float wn_s1 = v2.y * lap_s1 + 2.f * wvs.y - prvs.y + bsc.y * lap_b1;
        if (y == g_spos[2 * s]) {
            int sx = g_spos[2 * s + 1];
            if (sx == x0)      { wn_b0 += g_fbg[t * NS + s]; wn_s0 += g_fsc[t * NS + s]; }
            else if (sx == x1) { wn_b1 += g_fbg[t * NS + s]; wn_s1 += g_fsc[t * NS + s]; }
        }
        *(float2*)(g_wb[nxt] + idx) = make_float2(wn_b0, wn_b1);
        *(float2*)(g_ws[nxt] + idx) = make_float2(wn_s0, wn_s1);
    }
}

__global__ void finalize(const int* __restrict__ rloc, const int* __restrict__ rbloc,
                         void* __restrict__ out) {
    int i = blockIdx.x * blockDim.x + threadIdx.x;
    const float* wb0 = g_wb[0];   // NT even: newest field in buffer 0
    const float* ws0 = g_ws[0];
    if (i < SNP2) {
        out_st(out, i,        wb0[i]);
        out_st(out, SNP2 + i, ws0[i]);
    }
    if (i < 2 * NS * NREC) {      // record last step (t = NT-1)
        bool isbg = i < NS * NREC;
        int k = isbg ? i : i - NS * NREC;
        int s = k / NREC, r = k % NREC;
        const int* rl = isbg ? rbloc : rloc;
        int ry = clampi(rl[(s * NREC + r) * 2 + 0], 0, NYX - 1) + PAD;
        int rx = clampi(rl[(s * NREC + r) * 2 + 1], 0, NYX - 1) + PAD;
        const float* w = isbg ? wb0 : ws0;
        float val = w[s * NP2 + ry * NP + rx];
        int base = isbg ? (2 * SNP2) : (2 * SNP2 + NS * NREC * NT);
        out_st(out, base + (s * NREC + r) * NT + (NT - 1), val);
    }
}

extern "C" void kernel_launch(void* const* d_in, const int* in_sizes, int n_in,
                              void* d_out, int out_size, void* d_ws, size_t ws_size,
                              hipStream_t stream) {
    const void* v   = d_in[0];
    const void* sc  = d_in[1];
    const void* amp = d_in[2];
    const int* sloc  = (const int*)d_in[3];
    const int* rloc  = (const int*)d_in[4];
    const int* rbloc = (const int*)d_in[5];

    detect_mode<<<1, 64, 0, stream>>>(v);
    zero_state<<<(NP2 + 255) / 256, 256, 0, stream>>>();
    prep_pad<<<(NP2 + 255) / 256, 256, 0, stream>>>(v, sc);
    prep_src<<<(NT * NS + 255) / 256, 256, 0, stream>>>(amp, sloc, v, sc);

    dim3 grid(1, NP / 2, NS);            // 222 strips x 4 shots
    for (int t = 0; t < NT; ++t)
        step_fused<<<grid, 256, 0, stream>>>(t, rloc, rbloc, d_out);

    finalize<<<(SNP2 + 255) / 256, 256, 0, stream>>>(rloc, rbloc, d_out);
}

// Round 11
// 3829.094 us; speedup vs baseline: 1.1906x; 1.1906x over previous
//
#include <hip/hip_runtime.h>
#include <hip/hip_bf16.h>

// ScalarBorn: 4th-order FD scalar wave + Born scattering with CPML, MI355X.
// R11: R9 skeleton (1776 light blocks, 256 thr x 2 pts, 2 barriers) with
// bg/scattered fields INTERLEAVED as (b,s) pairs in all state arrays ->
// every paired global access is one float4 (interior loads 16->7, stores
// 2->1, addressing halved). R8/R10 proved per-block aggregation regresses;
// R9 proved instruction-count is the lever. Layout change only.

constexpr int NYX  = 400;
constexpr int NS   = 4;
constexpr int NREC = 100;
constexpr int NT   = 300;
constexpr int PAD  = 22;
constexpr int NP   = 444;
constexpr int NP2  = NP * NP;          // 197136
constexpr int SNP2 = NS * NP2;         // 788544
constexpr float DT    = 0.0005f;
constexpr float INVH  = 0.2f;
constexpr float INVH2 = 0.04f;
constexpr float C1A = 1.0f / 12.0f;
constexpr float C1B = 2.0f / 3.0f;
constexpr float C2A = -1.0f / 12.0f;
constexpr float C2B = 4.0f / 3.0f;
constexpr float C2C = -2.5f;

// interleaved state: element (b,s) pair for grid index idx lives at [2*idx, 2*idx+1]
__device__ __align__(16) float g_w[2][2 * SNP2];   // wavefield ping-pong
__device__ __align__(16) float g_px[2][2 * SNP2];  // psi_x dbuf
__device__ __align__(16) float g_py[2][2 * SNP2];  // psi_y dbuf
__device__ __align__(16) float g_zx[2 * SNP2];     // zeta_x
__device__ __align__(16) float g_zy[2 * SNP2];     // zeta_y
__device__ __align__(16) float g_vb[2 * NP2];      // (v2dt2, bscale) pairs
__device__ float g_pa[NP];
__device__ float g_pb[NP];
__device__ float g_fbg[NT * NS];
__device__ float g_fsc[NT * NS];
__device__ int   g_spos[2 * NS];
__device__ int   g_mode;               // 1 = bf16 io, 0 = f32 io

__device__ __forceinline__ int clampi(int v, int lo, int hi) {
    return v < lo ? lo : (v > hi ? hi : v);
}
__device__ __forceinline__ float in_ld(const void* p, int i) {
    if (g_mode) return __bfloat162float(((const __hip_bfloat16*)p)[i]);
    return ((const float*)p)[i];
}
__device__ __forceinline__ void out_st(void* p, int i, float v) {
    if (g_mode) ((__hip_bfloat16*)p)[i] = __float2bfloat16(v);
    else        ((float*)p)[i] = v;
}
// float4 = (b0,s0,b1,s1) at row yy, col pair (2i,2i+1) of shot s; 0 if row OOB
__device__ __forceinline__ float4 ld4(const float* w, int s, int yy, int i) {
    if ((unsigned)yy >= (unsigned)NP) return make_float4(0.f, 0.f, 0.f, 0.f);
    return *(const float4*)(w + 2 * (s * NP2 + yy * NP + 2 * i));
}

__global__ void detect_mode(const void* vptr) {
    if (threadIdx.x == 0 && blockIdx.x == 0) {
        const __hip_bfloat16* p = (const __hip_bfloat16*)vptr;
        int ok = 1;
        for (int i = 0; i < 32; i += 2) {
            float f = __bfloat162float(p[i]);
            if (!(f >= 1000.f && f <= 3000.f)) ok = 0;
        }
        g_mode = ok;
    }
}

__global__ void zero_state() {
    int i = blockIdx.x * blockDim.x + threadIdx.x;
    if (i >= SNP2 / 2) return;           // each array = 2*SNP2 floats = SNP2/2 float4
    float4 z = make_float4(0.f, 0.f, 0.f, 0.f);
    ((float4*)g_w[0])[i] = z;  ((float4*)g_w[1])[i] = z;
    ((float4*)g_px[0])[i] = z; ((float4*)g_px[1])[i] = z;
    ((float4*)g_py[0])[i] = z; ((float4*)g_py[1])[i] = z;
    ((float4*)g_zx)[i] = z;    ((float4*)g_zy)[i] = z;
}

__global__ void prep_pad(const void* __restrict__ v, const void* __restrict__ sc) {
    int i = blockIdx.x * blockDim.x + threadIdx.x;
    if (i >= NP2) return;
    int y = i / NP, x = i % NP;
    int vy = clampi(y - PAD, 0, NYX - 1);
    int vx = clampi(x - PAD, 0, NYX - 1);
    float vv = in_ld(v, vy * NYX + vx);
    float vd = vv * DT;
    float s = 0.f;
    if (y >= PAD && y < PAD + NYX && x >= PAD && x < PAD + NYX)
        s = in_ld(sc, (y - PAD) * NYX + (x - PAD));
    g_vb[2 * i]     = vd * vd;
    g_vb[2 * i + 1] = 2.f * vv * s * DT * DT;
    if (i < NP) {
        float fi = (float)i;
        float f1 = fminf(fmaxf((22.f - fi) * 0.05f, 0.f), 1.f);
        float f2 = fminf(fmaxf((fi - 421.f) * 0.05f, 0.f), 1.f);
        float frac = fmaxf(f1, f2);
        float sigma = 259.0408229f * frac * frac;
        const float alpha = 78.53981634f;
        float a = expf(-(sigma + alpha) * DT);
        g_pa[i] = a;
        g_pb[i] = (sigma > 0.f) ? sigma / (sigma + alpha) * (a - 1.f) : 0.f;
    }
}

__global__ void prep_src(const void* __restrict__ amp, const int* __restrict__ sloc,
                         const void* __restrict__ v, const void* __restrict__ sc) {
    int i = blockIdx.x * blockDim.x + threadIdx.x;
    if (i >= NT * NS) return;
    int s = i % NS, t = i / NS;
    int ly = clampi(sloc[s * 2 + 0], 0, NYX - 1);
    int lx = clampi(sloc[s * 2 + 1], 0, NYX - 1);
    float a  = in_ld(amp, s * NT + t);
    float vv = in_ld(v,  ly * NYX + lx);
    float ss = in_ld(sc, ly * NYX + lx);
    g_fbg[i] = -a * vv * vv * DT * DT;
    g_fsc[i] = -2.f * a * vv * ss * DT * DT;
    if (i < NS) {
        g_spos[2 * i]     = ly + PAD;
        g_spos[2 * i + 1] = lx + PAD;
    }
}

// one fused timestep. Block = row y of shot s; 256 threads x 2 points.
// LDS layout: (b,s) pair of logical col c at float index 2*(c+2); pads zeroed.
__global__ void __launch_bounds__(256)
step_fused(int t, const int* __restrict__ rloc, const int* __restrict__ rbloc,
           void* __restrict__ out) {
    const int i = threadIdx.x;
    const int y = blockIdx.y;
    const int s = blockIdx.z;
    const int cur = t & 1, nxt = cur ^ 1;
    __shared__ __align__(16) float sw[904], spx[904];

    if (t > 0 && y == 0 && i < 2 * NREC) {    // record step t-1
        int r = i % NREC;
        bool isbg = i < NREC;
        const int* rl = isbg ? rbloc : rloc;
        int ry = clampi(rl[(s * NREC + r) * 2 + 0], 0, NYX - 1) + PAD;
        int rx = clampi(rl[(s * NREC + r) * 2 + 1], 0, NYX - 1) + PAD;
        float val = g_w[cur][2 * (s * NP2 + ry * NP + rx) + (isbg ? 0 : 1)];
        int base = isbg ? (2 * SNP2) : (2 * SNP2 + NS * NREC * NT);
        out_st(out, base + (s * NREC + r) * NT + (t - 1), val);
    }

    const bool active = i < 222;
    const int x0 = 2 * i, x1 = x0 + 1;
    const int yx  = y * NP + x0;
    const int idx = s * NP2 + yx;

    float4 w4 = make_float4(0.f, 0.f, 0.f, 0.f);   // (b0,s0,b1,s1)
    if (active) {
        w4 = *(const float4*)(g_w[cur] + 2 * idx);
        *(float4*)&sw[2 * x0 + 4] = w4;
    } else if (i == 222) {
        #pragma unroll
        for (int k = 0; k < 4; ++k) { sw[k] = 0.f; spx[k] = 0.f; }
    } else if (i == 223) {
        #pragma unroll
        for (int k = 892; k < 904; ++k) { sw[k] = 0.f; spx[k] = 0.f; }
    }
    __syncthreads();

    // ---- x stencils from LDS + own psi_x updates ----
    const bool pxreg = (i <= 11 || i >= 210);
    float pbx0 = 0.f, pbx1 = 0.f, pax0 = 0.f, pax1 = 0.f;
    float d2x_b0 = 0.f, d2x_b1 = 0.f, d2x_s0 = 0.f, d2x_s1 = 0.f;
    float4 pxn = make_float4(0.f, 0.f, 0.f, 0.f);
    float2 tm2, tm1, tp2, tp3;
    if (active) {
        tm2 = *(const float2*)&sw[2 * (x0 - 2) + 4];
        tm1 = *(const float2*)&sw[2 * (x0 - 1) + 4];
        tp2 = *(const float2*)&sw[2 * (x0 + 2) + 4];
        tp3 = *(const float2*)&sw[2 * (x0 + 3) + 4];
        d2x_b0 = (C2A * (tm2.x + tp2.x) + C2B * (tm1.x + w4.z) + C2C * w4.x) * INVH2;
        d2x_s0 = (C2A * (tm2.y + tp2.y) + C2B * (tm1.y + w4.w) + C2C * w4.y) * INVH2;
        d2x_b1 = (C2A * (tm1.x + tp3.x) + C2B * (w4.x + tp2.x) + C2C * w4.z) * INVH2;
        d2x_s1 = (C2A * (tm1.y + tp3.y) + C2B * (w4.y + tp2.y) + C2C * w4.w) * INVH2;
        pbx0 = g_pb[x0]; pbx1 = g_pb[x1];
        pax0 = g_pa[x0]; pax1 = g_pa[x1];
        if (pxreg && pbx0 != 0.f) {      // pb pair-uniform (frame edges even)
            float4 pxo = *(const float4*)(g_px[cur] + 2 * idx);
            float dwb0 = (C1A * tm2.x - C1B * tm1.x + C1B * w4.z - C1A * tp2.x) * INVH;
            float dws0 = (C1A * tm2.y - C1B * tm1.y + C1B * w4.w - C1A * tp2.y) * INVH;
            float dwb1 = (C1A * tm1.x - C1B * w4.x + C1B * tp2.x - C1A * tp3.x) * INVH;
            float dws1 = (C1A * tm1.y - C1B * w4.y + C1B * tp2.y - C1A * tp3.y) * INVH;
            pxn.x = pax0 * pxo.x + pbx0 * dwb0;
            pxn.y = pax0 * pxo.y + pbx0 * dws0;
            pxn.z = pax1 * pxo.z + pbx1 * dwb1;
            pxn.w = pax1 * pxo.w + pbx1 * dws1;
            *(float4*)(g_px[nxt] + 2 * idx) = pxn;
        }
        *(float4*)&spx[2 * x0 + 4] = pxn;
    }
    __syncthreads();
    if (!active) return;

    // ---- dpsi_x from LDS psi_x_new ----
    float dpx_b0 = 0.f, dpx_b1 = 0.f, dpx_s0 = 0.f, dpx_s1 = 0.f;
    if (pxreg) {
        float2 pm2 = *(const float2*)&spx[2 * (x0 - 2) + 4];
        float2 pm1 = *(const float2*)&spx[2 * (x0 - 1) + 4];
        float2 pp2 = *(const float2*)&spx[2 * (x0 + 2) + 4];
        float2 pp3 = *(const float2*)&spx[2 * (x0 + 3) + 4];
        dpx_b0 = (C1A * pm2.x - C1B * pm1.x + C1B * pxn.z - C1A * pp2.x) * INVH;
        dpx_s0 = (C1A * pm2.y - C1B * pm1.y + C1B * pxn.w - C1A * pp2.y) * INVH;
        dpx_b1 = (C1A * pm1.x - C1B * pxn.x + C1B * pp2.x - C1A * pp3.x) * INVH;
        dpx_s1 = (C1A * pm1.y - C1B * pxn.y + C1B * pp2.y - C1A * pp3.y) * INVH;
    }

    // ---- y direction ----
    const float pby = g_pb[y];               // block-uniform
    const bool yframe = (y <= 23 || y >= 420);
    float d2y_b0, d2y_b1, d2y_s0, d2y_s1;
    float dpy_b0 = 0.f, dpy_b1 = 0.f, dpy_s0 = 0.f, dpy_s1 = 0.f;
    if (yframe) {
        float4 wy[9];                        // rows y-4..y+4, (b0,s0,b1,s1)
        #pragma unroll
        for (int k = 0; k < 9; ++k)
            wy[k] = (k == 4) ? w4 : ld4(g_w[cur], s, y - 4 + k, i);
        d2y_b0 = (C2A * (wy[2].x + wy[6].x) + C2B * (wy[3].x + wy[5].x) + C2C * wy[4].x) * INVH2;
        d2y_s0 = (C2A * (wy[2].y + wy[6].y) + C2B * (wy[3].y + wy[5].y) + C2C * wy[4].y) * INVH2;
        d2y_b1 = (C2A * (wy[2].z + wy[6].z) + C2B * (wy[3].z + wy[5].z) + C2C * wy[4].z) * INVH2;
        d2y_s1 = (C2A * (wy[2].w + wy[6].w) + C2B * (wy[3].w + wy[5].w) + C2C * wy[4].w) * INVH2;
        float4 pn[5];                        // psi_y_new rows y-2..y+2
        #pragma unroll
        for (int k = 0; k < 5; ++k) {
            int yy = y - 2 + k;
            float pbv = ((unsigned)yy < (unsigned)NP) ? g_pb[yy] : 0.f;  // uniform
            float4 r = make_float4(0.f, 0.f, 0.f, 0.f);
            if (pbv != 0.f) {
                float pav = g_pa[yy];
                float4 po = *(const float4*)(g_py[cur] + 2 * (s * NP2 + yy * NP + x0));
                float db0 = (C1A * wy[k].x - C1B * wy[k+1].x + C1B * wy[k+3].x - C1A * wy[k+4].x) * INVH;
                float ds0 = (C1A * wy[k].y - C1B * wy[k+1].y + C1B * wy[k+3].y - C1A * wy[k+4].y) * INVH;
                float db1 = (C1A * wy[k].z - C1B * wy[k+1].z + C1B * wy[k+3].z - C1A * wy[k+4].z) * INVH;
                float ds1 = (C1A * wy[k].w - C1B * wy[k+1].w + C1B * wy[k+3].w - C1A * wy[k+4].w) * INVH;
                r.x = pav * po.x + pbv * db0;  r.y = pav * po.y + pbv * ds0;
                r.z = pav * po.z + pbv * db1;  r.w = pav * po.w + pbv * ds1;
            }
            pn[k] = r;
        }
        dpy_b0 = (C1A * pn[0].x - C1B * pn[1].x + C1B * pn[3].x - C1A * pn[4].x) * INVH;
        dpy_s0 = (C1A * pn[0].y - C1B * pn[1].y + C1B * pn[3].y - C1A * pn[4].y) * INVH;
        dpy_b1 = (C1A * pn[0].z - C1B * pn[1].z + C1B * pn[3].z - C1A * pn[4].z) * INVH;
        dpy_s1 = (C1A * pn[0].w - C1B * pn[1].w + C1B * pn[3].w - C1A * pn[4].w) * INVH;
        if (pby != 0.f)
            *(float4*)(g_py[nxt] + 2 * idx) = pn[2];
    } else {                                 // interior: 4 float4 row loads
        float4 m2 = *(const float4*)(g_w[cur] + 2 * (idx - 2 * NP));
        float4 m1 = *(const float4*)(g_w[cur] + 2 * (idx - NP));
        float4 p1 = *(const float4*)(g_w[cur] + 2 * (idx + NP));
        float4 p2 = *(const float4*)(g_w[cur] + 2 * (idx + 2 * NP));
        d2y_b0 = (C2A * (m2.x + p2.x) + C2B * (m1.x + p1.x) + C2C * w4.x) * INVH2;
        d2y_s0 = (C2A * (m2.y + p2.y) + C2B * (m1.y + p1.y) + C2C * w4.y) * INVH2;
        d2y_b1 = (C2A * (m2.z + p2.z) + C2B * (m1.z + p1.z) + C2C * w4.z) * INVH2;
        d2y_s1 = (C2A * (m2.w + p2.w) + C2B * (m1.w + p1.w) + C2C * w4.w) * INVH2;
    }

    // ---- zeta (in-place, own points, paired float4) ----
    float zy_b0 = 0.f, zy_b1 = 0.f, zy_s0 = 0.f, zy_s1 = 0.f;
    float zx_b0 = 0.f, zx_b1 = 0.f, zx_s0 = 0.f, zx_s1 = 0.f;
    if (pby != 0.f) {
        float pay = g_pa[y];
        float4 zo = *(const float4*)(g_zy + 2 * idx);
        zy_b0 = pay * zo.x + pby * (d2y_b0 + dpy_b0);
        zy_s0 = pay * zo.y + pby * (d2y_s0 + dpy_s0);
        zy_b1 = pay * zo.z + pby * (d2y_b1 + dpy_b1);
        zy_s1 = pay * zo.w + pby * (d2y_s1 + dpy_s1);
        *(float4*)(g_zy + 2 * idx) = make_float4(zy_b0, zy_s0, zy_b1, zy_s1);
    }
    if (pbx0 != 0.f) {                       // pair-uniform
        float4 zo = *(const float4*)(g_zx + 2 * idx);
        zx_b0 = pax0 * zo.x + pbx0 * (d2x_b0 + dpx_b0);
        zx_s0 = pax0 * zo.y + pbx0 * (d2x_s0 + dpx_s0);
        zx_b1 = pax1 * zo.z + pbx1 * (d2x_b1 + dpx_b1);
        zx_s1 = pax1 * zo.w + pbx1 * (d2x_s1 + dpx_s1);
        *(float4*)(g_zx + 2 * idx) = make_float4(zx_b0, zx_s0, zx_b1, zx_s1);
    }

    // ---- lap + leapfrog + Born + source ----
    float4 vb   = *(const float4*)(g_vb + 2 * yx);        // (v0,bs0,v1,bs1)
    float4 prev = *(const float4*)(g_w[nxt] + 2 * idx);
    float lap_b0 = d2y_b0 + d2x_b0 + dpy_b0 + dpx_b0 + zy_b0 + zx_b0;
    float lap_s0 = d2y_s0 + d2x_s0 + dpy_s0 + dpx_s0 + zy_s0 + zx_s0;
    float lap_b1 = d2y_b1 + d2x_b1 + dpy_b1 + dpx_b1 + zy_b1 + zx_b1;
    float lap_s1 = d2y_s1 + d2x_s1 + dpy_s1 + dpx_s1 + zy_s1 + zx_s1;
    float wn_b0 = vb.x * lap_b0 + 2.f * w4.x - prev.x;
    float wn_s0 = vb.x * lap_s0 + 2.f * w4.y - prev.y + vb.y * lap_b0;
    float wn_b1 = vb.z * lap_b1 + 2.f * w4.z - prev.z;
    float wn_s1 = vb.z * lap_s1 + 2.f * w4.w - prev.w + vb.w * lap_b1;
    if (y == g_spos[2 * s]) {
        int sx = g_spos[2 * s + 1];
        if (sx == x0)      { wn_b0 += g_fbg[t * NS + s]; wn_s0 += g_fsc[t * NS + s]; }
        else if (sx == x1) { wn_b1 += g_fbg[t * NS + s]; wn_s1 += g_fsc[t * NS + s]; }
    }
    *(float4*)(g_w[nxt] + 2 * idx) = make_float4(wn_b0, wn_s0, wn_b1, wn_s1);
}

__global__ void finalize(const int* __restrict__ rloc, const int* __restrict__ rbloc,
                         void* __restrict__ out) {
    int i = blockIdx.x * blockDim.x + threadIdx.x;
    const float* w0 = g_w[0];     // NT even: newest field in buffer 0
    if (i < SNP2) {
        out_st(out, i,        w0[2 * i]);       // bg flat
        out_st(out, SNP2 + i, w0[2 * i + 1]);   // scattered flat
    }
    if (i < 2 * NS * NREC) {      // record last step (t = NT-1)
        bool isbg = i < NS * NREC;
        int k = isbg ? i : i - NS * NREC;
        int s = k / NREC, r = k % NREC;
        const int* rl = isbg ? rbloc : rloc;
        int ry = clampi(rl[(s * NREC + r) * 2 + 0], 0, NYX - 1) + PAD;
        int rx = clampi(rl[(s * NREC + r) * 2 + 1], 0, NYX - 1) + PAD;
        float val = w0[2 * (s * NP2 + ry * NP + rx) + (isbg ? 0 : 1)];
        int base = isbg ? (2 * SNP2) : (2 * SNP2 + NS * NREC * NT);
        out_st(out, base + (s * NREC + r) * NT + (NT - 1), val);
    }
}

extern "C" void kernel_launch(void* const* d_in, const int* in_sizes, int n_in,
                              void* d_out, int out_size, void* d_ws, size_t ws_size,
                              hipStream_t stream) {
    const void* v   = d_in[0];
    const void* sc  = d_in[1];
    const void* amp = d_in[2];
    const int* sloc  = (const int*)d_in[3];
    const int* rloc  = (const int*)d_in[4];
    const int* rbloc = (const int*)d_in[5];

    detect_mode<<<1, 64, 0, stream>>>(v);
    zero_state<<<(SNP2 / 2 + 255) / 256, 256, 0, stream>>>();
    prep_pad<<<(NP2 + 255) / 256, 256, 0, stream>>>(v, sc);
    prep_src<<<(NT * NS + 255) / 256, 256, 0, stream>>>(amp, sloc, v, sc);

    dim3 grid(1, NP, NS);
    for (int t = 0; t < NT; ++t)
        step_fused<<<grid, 256, 0, stream>>>(t, rloc, rbloc, d_out);

    finalize<<<(SNP2 + 255) / 256, 256, 0, stream>>>(rloc, rbloc, d_out);
}